// Round 4
// baseline (462.042 us; speedup 1.0000x reference)
//
#include <hip/hip_runtime.h>

// KVCacheManager: out[0] = transpose(K[:, :, :, :S]) (B,H,D,S)->(B,H,S,D)
//                 out[1] = V[:, :, :S, :] contiguous copy
// Pure data movement, fp32. Nominal traffic 402 MB (~64 us @6.3 TB/s).
//
// Round 6 = DIAGNOSTIC round. Four structural variants (scalar-LDS, DMA+
// swizzle, contiguous-store tile, NT/plain cache steering) all measured
// 354-361 us total; the kernel's own rocprof row has never been visible
// (fills ~120 us always top the top-5 sort). This round keeps Round-3's
// kernel EXACTLY and adds a 180 us deadline-spin on ONE thread of ONE
// block so the kernel dispatch tops the sort and exposes its true
// FETCH_SIZE / WRITE_SIZE / duration:
//   work_us = 355.2 + 180 - new_total
//   kernel WRITE_SIZE >> 200 MB  -> poison-writeback debt in our window
//   kernel FETCH_SIZE >> 200 MB  -> hidden over-fetch
//   both ~200 MB                 -> latency-bound, attack concurrency
// Spin cost: one wave-slot on one CU (~0.4% perturbation), absmax
// unaffected, no API calls (graph-capture safe).

#define BH 32          // B*H = 4*8
#define DD 128         // head dim
#define SPIN_TICKS 18000LL   // 180 us at 100 MHz s_memrealtime

typedef float f4 __attribute__((ext_vector_type(4)));

__device__ __forceinline__ void gload_lds16_nt(const float* g, float* l) {
    __builtin_amdgcn_global_load_lds(
        (const __attribute__((address_space(1))) void*)g,
        (__attribute__((address_space(3))) void*)l,
        16, 0, 2);
}

__global__ __launch_bounds__(256) void kv_repack(
    const float* __restrict__ kc, const float* __restrict__ vc,
    float* __restrict__ out,
    int S, int Sfull, int sTiles, int vBlocksPerBH, int f4PerVBlock)
{
    __shared__ float lds[128 * 64];   // 32,768 B: [d][16 f4-slots of s]

    const int bid = blockIdx.x;
    const int t = threadIdx.x;
    const int r3 = bid % 3;           // 0,1 -> K ; 2 -> V  (2K:1V interleave)

    if (r3 != 2) {
        // ---- K transpose: one block = 128(d) x 64(s) tile ----
        const int kb    = (bid / 3) * 2 + r3;   // 0..kBlocks-1
        const int bh    = kb / sTiles;
        const int sTile = kb - bh * sTiles;

        const int wave = t >> 6;                // 0..3
        const int lane = t & 63;

        // stage 1: global -> LDS DMA (NT). 4 d-rows x 16 f4-slots per instr,
        // LDS dest linear; source slot pre-swizzled (involution re-applied
        // on the stage-2 read): LDS[d][c] = K[d][4*(c ^ ((d>>2)&7)) ..+3].
        {
            const int c  = lane & 15;           // f4 slot within 64-s row
            const int dh = lane >> 4;           // 0..3
            const float* rowbase = kc
                + (size_t)(bh * DD) * (size_t)Sfull
                + (size_t)(sTile << 6);
#pragma unroll
            for (int i = 0; i < 8; ++i) {
                const int dbase = (wave << 5) + (i << 2);   // 32w + 4i
                const int d  = dbase + dh;                  // 0..127
                const int s4 = c ^ ((d >> 2) & 7);          // source swizzle
                gload_lds16_nt(rowbase + (size_t)d * Sfull + (s4 << 2),
                               &lds[dbase << 6]);
            }
        }
        __syncthreads();

        // stage 2: LDS -> global. 1 KB contiguous store per wave instr;
        // block output = contiguous 32 KB.
        {
            const int d4 = t & 31;              // f4 column in d (full 128)
            const int r0 = t >> 5;              // 0..7
            const int swz = d4 & 7;             // (d'>>2)&7 for d'=4*d4+k
            float* dstBase = out
                + ((size_t)bh * S + (size_t)(sTile << 6)) * DD
                + (d4 << 2);
#pragma unroll
            for (int i = 0; i < 8; ++i) {
                const int sr   = (i << 3) + r0; // 0..63
                const int base = (d4 << 8)
                               + ((((sr >> 2) ^ swz) << 2) + (sr & 3));
                f4 v;
                v.x = lds[base];
                v.y = lds[base + 64];
                v.z = lds[base + 128];
                v.w = lds[base + 192];
                *(f4*)(dstBase + (size_t)sr * DD) = v;
            }
        }
    } else {
        // ---- V copy: NT loads, plain stores, MLP=4 ----
        const int vb   = bid / 3;
        const int bh   = vb / vBlocksPerBH;
        const int part = vb - bh * vBlocksPerBH;

        const size_t f4PerBHsrc = (size_t)Sfull * (DD / 4);
        const size_t f4PerBHdst = (size_t)S * (DD / 4);
        const size_t outVOff    = (size_t)BH * S * (DD / 4);

        const f4* src = (const f4*)vc + (size_t)bh * f4PerBHsrc
                        + (size_t)part * f4PerVBlock;
        f4* dst = (f4*)out + outVOff + (size_t)bh * f4PerBHdst
                  + (size_t)part * f4PerVBlock;

        const int n = f4PerVBlock;
        int j = t;
        for (; j + 768 < n; j += 1024) {
            f4 a0 = __builtin_nontemporal_load(src + j);
            f4 a1 = __builtin_nontemporal_load(src + j + 256);
            f4 a2 = __builtin_nontemporal_load(src + j + 512);
            f4 a3 = __builtin_nontemporal_load(src + j + 768);
            dst[j]       = a0;
            dst[j + 256] = a1;
            dst[j + 512] = a2;
            dst[j + 768] = a3;
        }
        for (; j < n; j += 256) {
            f4 a = __builtin_nontemporal_load(src + j);
            dst[j] = a;
        }
    }

    // ---- diagnostic deadline-spin: surface this kernel in rocprof top-5 ----
    if (bid == 0 && t == 0) {
        const unsigned long long t0 = __builtin_amdgcn_s_memrealtime();
        while ((long long)(__builtin_amdgcn_s_memrealtime() - t0) < SPIN_TICKS) {
            __builtin_amdgcn_s_sleep(8);
        }
    }
}

extern "C" void kernel_launch(void* const* d_in, const int* in_sizes, int n_in,
                              void* d_out, int out_size, void* d_ws, size_t ws_size,
                              hipStream_t stream) {
    const float* kc = (const float*)d_in[0];
    const float* vc = (const float*)d_in[1];
    float* out = (float*)d_out;

    // Derive shapes host-side: out = (2, B,H, S, D)
    const int S     = out_size / (2 * BH * DD);          // 6144
    const int Sfull = in_sizes[0] / (BH * DD);           // 8192

    const int sTiles        = S >> 6;                    // 96 (64-wide s tiles)
    const int kBlocks       = BH * sTiles;               // 3072
    const int vBlocksPerBH  = S >> 7;                    // 48
    const int f4PerVBlock   = (S * (DD / 4)) / vBlocksPerBH; // 4096
    const int vBlocks       = BH * vBlocksPerBH;         // 1536
    // interleave mapping requires kBlocks == 2*vBlocks (holds: 3072 = 2*1536)

    dim3 grid(kBlocks + vBlocks);
    dim3 block(256);
    kv_repack<<<grid, block, 0, stream>>>(kc, vc, out, S, Sfull,
                                          sTiles, vBlocksPerBH, f4PerVBlock);
}

// Round 5
// 349.453 us; speedup vs baseline: 1.3222x; 1.3222x over previous
//
#include <hip/hip_runtime.h>

// KVCacheManager: out[0] = transpose(K[:, :, :, :S]) (B,H,D,S)->(B,H,S,D)
//                 out[1] = V[:, :, :S, :] contiguous copy
// Pure data movement, fp32. Nominal traffic 402 MB.
//
// Round-4 diagnostic (deadline-spin) established ground truth:
//   real kernel work ~82 us; WRITE_SIZE == 201.3 MB exactly (no writeback
//   debt); FETCH_SIZE == 98 MB (reads 50% cache-hit, no over-fetch);
//   SQ_LDS_BANK_CONFLICT = 2.36M cyc (~5 us) -- stage-2 was 4-way banked,
//   not 2-way: bank = (slot&7)*4 + q had q in {0,1} per wave (16 banks).
// Floor: 402 MB at fill-rate 6.6 TB/s ~= 61 us.
//
// Round 7 (fix the measured losses):
//   1. Stage-2 lane remap: d4 = (wave&1)*16 + (t&15), q = (t>>4)&3,
//      sr = q + 4*(t>>7) + 8*i. Bank = ((jb+2i)^(d4&7))*4 + q spans all
//      32 banks, 2 lanes/bank = free. (Store instrs become 4x256B
//      segments -- store contiguity already proven non-critical R1->R2.)
//   2. V copy MLP 4 -> 8 (double outstanding bytes per wave).
//   3. All stores NT: writes stop evicting the L2-resident input lines
//      (FETCH shows 50% read-hit worth protecting).
// Structure otherwise unchanged: 128d x 64s K tile, stage-1 DMA
// global_load_lds + source swizzle s4 = c ^ ((d>>2)&7), 2K:1V interleave.

#define BH 32          // B*H = 4*8
#define DD 128         // head dim

typedef float f4 __attribute__((ext_vector_type(4)));

__device__ __forceinline__ void gload_lds16_nt(const float* g, float* l) {
    __builtin_amdgcn_global_load_lds(
        (const __attribute__((address_space(1))) void*)g,
        (__attribute__((address_space(3))) void*)l,
        16, 0, 2);
}

__global__ __launch_bounds__(256) void kv_repack(
    const float* __restrict__ kc, const float* __restrict__ vc,
    float* __restrict__ out,
    int S, int Sfull, int sTiles, int vBlocksPerBH, int f4PerVBlock)
{
    __shared__ float lds[128 * 64];   // 32,768 B: [d][16 f4-slots of s]

    const int bid = blockIdx.x;
    const int t = threadIdx.x;
    const int r3 = bid % 3;           // 0,1 -> K ; 2 -> V  (2K:1V interleave)

    if (r3 != 2) {
        // ---- K transpose: one block = 128(d) x 64(s) tile ----
        const int kb    = (bid / 3) * 2 + r3;   // 0..kBlocks-1
        const int bh    = kb / sTiles;
        const int sTile = kb - bh * sTiles;

        const int wave = t >> 6;                // 0..3
        const int lane = t & 63;

        // stage 1: global -> LDS DMA (NT). 4 d-rows x 16 f4-slots per instr,
        // LDS dest linear; source slot pre-swizzled (involution re-applied
        // on the stage-2 read): LDS[d][c] = K[d][4*(c ^ ((d>>2)&7)) ..+3].
        {
            const int c  = lane & 15;           // f4 slot within 64-s row
            const int dh = lane >> 4;           // 0..3
            const float* rowbase = kc
                + (size_t)(bh * DD) * (size_t)Sfull
                + (size_t)(sTile << 6);
#pragma unroll
            for (int i = 0; i < 8; ++i) {
                const int dbase = (wave << 5) + (i << 2);   // 32w + 4i
                const int d  = dbase + dh;                  // 0..127
                const int s4 = c ^ ((d >> 2) & 7);          // source swizzle
                gload_lds16_nt(rowbase + (size_t)d * Sfull + (s4 << 2),
                               &lds[dbase << 6]);
            }
        }
        __syncthreads();

        // stage 2: LDS -> global, conflict-free lane map.
        //   d4 = (wave&1)*16 + (t&15)   f4 column in d (0..31)
        //   q  = (t>>4)&3               sr & 3
        //   jb = t>>7                   0..1
        //   sr = q + 4*jb + 8*i         i = 0..7  (covers 0..63)
        // element (d'=4*d4+k, sr) at lds[(4*d4+k)*64 + slot*4 + q],
        // slot = (jb+2i) ^ (d4&7). Bank = (slot&7)*4 + q: d4&7 spans 8,
        // q spans 4 -> all 32 banks, 2 lanes/bank = free.
        {
            const int d4 = ((t >> 6) & 1) * 16 + (t & 15);
            const int q  = (t >> 4) & 3;
            const int jb = t >> 7;
            float* dstBase = out
                + ((size_t)bh * S + (size_t)(sTile << 6)) * DD
                + (d4 << 2);
#pragma unroll
            for (int i = 0; i < 8; ++i) {
                const int sr   = q + (jb << 2) + (i << 3);  // 0..63
                const int slot = (jb + 2 * i) ^ (d4 & 7);
                const int base = (d4 << 8) + (slot << 2) + q;
                f4 v;
                v.x = lds[base];
                v.y = lds[base + 64];
                v.z = lds[base + 128];
                v.w = lds[base + 192];
                __builtin_nontemporal_store(v, (f4*)(dstBase + (size_t)sr * DD));
            }
        }
    } else {
        // ---- V copy: NT loads, NT stores, MLP=8 ----
        const int vb   = bid / 3;
        const int bh   = vb / vBlocksPerBH;
        const int part = vb - bh * vBlocksPerBH;

        const size_t f4PerBHsrc = (size_t)Sfull * (DD / 4);
        const size_t f4PerBHdst = (size_t)S * (DD / 4);
        const size_t outVOff    = (size_t)BH * S * (DD / 4);

        const f4* src = (const f4*)vc + (size_t)bh * f4PerBHsrc
                        + (size_t)part * f4PerVBlock;
        f4* dst = (f4*)out + outVOff + (size_t)bh * f4PerBHdst
                  + (size_t)part * f4PerVBlock;

        const int n = f4PerVBlock;
        int j = t;
        for (; j + 1792 < n; j += 2048) {
            f4 a0 = __builtin_nontemporal_load(src + j);
            f4 a1 = __builtin_nontemporal_load(src + j + 256);
            f4 a2 = __builtin_nontemporal_load(src + j + 512);
            f4 a3 = __builtin_nontemporal_load(src + j + 768);
            f4 a4 = __builtin_nontemporal_load(src + j + 1024);
            f4 a5 = __builtin_nontemporal_load(src + j + 1280);
            f4 a6 = __builtin_nontemporal_load(src + j + 1536);
            f4 a7 = __builtin_nontemporal_load(src + j + 1792);
            __builtin_nontemporal_store(a0, dst + j);
            __builtin_nontemporal_store(a1, dst + j + 256);
            __builtin_nontemporal_store(a2, dst + j + 512);
            __builtin_nontemporal_store(a3, dst + j + 768);
            __builtin_nontemporal_store(a4, dst + j + 1024);
            __builtin_nontemporal_store(a5, dst + j + 1280);
            __builtin_nontemporal_store(a6, dst + j + 1536);
            __builtin_nontemporal_store(a7, dst + j + 1792);
        }
        for (; j < n; j += 256) {
            f4 a = __builtin_nontemporal_load(src + j);
            __builtin_nontemporal_store(a, dst + j);
        }
    }
}

extern "C" void kernel_launch(void* const* d_in, const int* in_sizes, int n_in,
                              void* d_out, int out_size, void* d_ws, size_t ws_size,
                              hipStream_t stream) {
    const float* kc = (const float*)d_in[0];
    const float* vc = (const float*)d_in[1];
    float* out = (float*)d_out;

    // Derive shapes host-side: out = (2, B,H, S, D)
    const int S     = out_size / (2 * BH * DD);          // 6144
    const int Sfull = in_sizes[0] / (BH * DD);           // 8192

    const int sTiles        = S >> 6;                    // 96 (64-wide s tiles)
    const int kBlocks       = BH * sTiles;               // 3072
    const int vBlocksPerBH  = S >> 7;                    // 48
    const int f4PerVBlock   = (S * (DD / 4)) / vBlocksPerBH; // 4096
    const int vBlocks       = BH * vBlocksPerBH;         // 1536
    // interleave mapping requires kBlocks == 2*vBlocks (holds: 3072 = 2*1536)

    dim3 grid(kBlocks + vBlocks);
    dim3 block(256);
    kv_repack<<<grid, block, 0, stream>>>(kc, vc, out, S, Sfull,
                                          sTiles, vBlocksPerBH, f4PerVBlock);
}